// Round 2
// baseline (3537.049 us; speedup 1.0000x reference)
//
#include <hip/hip_runtime.h>
#include <hip/hip_bf16.h>

#define N_NODES 30000
#define N_EDGES 510000
#define K_DIM   128

typedef short bf16x8 __attribute__((ext_vector_type(8)));
typedef float f32x4  __attribute__((ext_vector_type(4)));
typedef float f32x2  __attribute__((ext_vector_type(2)));

template<int M> struct VT;
template<> struct VT<256> { using T = f32x4; static constexpr int V = 4; };
template<> struct VT<128> { using T = f32x2; static constexpr int V = 2; };

// ---------------- fp32 -> bf16 convert ----------------
__global__ void convert_kernel(const float* __restrict__ x, __hip_bfloat16* __restrict__ y, int n) {
  int i = blockIdx.x * blockDim.x + threadIdx.x;
  if (i < n) y[i] = __float2bfloat16(x[i]);
}

// ---------------- W transpose (K x M fp32) -> (M x K bf16) ----------------
__global__ void transpose_w_kernel(const float* __restrict__ W,
                                   __hip_bfloat16* __restrict__ Wt, int K, int M) {
  int i = blockIdx.x * blockDim.x + threadIdx.x;
  if (i < K * M) {
    int k = i / M, m = i - k * M;
    Wt[m * K + k] = __float2bfloat16(W[i]);
  }
}

// ---------------- degree (in-degree by dst) ----------------
__global__ void deg_kernel(const int* __restrict__ dst, int* __restrict__ deg, int e) {
  int i = blockIdx.x * blockDim.x + threadIdx.x;
  if (i < e) atomicAdd(&deg[dst[i]], 1);
}

// ---------------- exclusive scan over deg -> offsets (+cursor copy), 1 block ----------------
__global__ void scan_kernel(const int* __restrict__ deg, int* __restrict__ off,
                            int* __restrict__ cur, int n) {
  __shared__ int buf[1024];
  int tid = threadIdx.x;
  int running = 0;
  for (int base = 0; base < n; base += 1024) {
    int v = (base + tid < n) ? deg[base + tid] : 0;
    buf[tid] = v;
    __syncthreads();
    for (int o = 1; o < 1024; o <<= 1) {
      int t = (tid >= o) ? buf[tid - o] : 0;
      __syncthreads();
      buf[tid] += t;
      __syncthreads();
    }
    int incl = buf[tid];
    if (base + tid < n) {
      int excl = running + incl - v;
      off[base + tid] = excl;
      cur[base + tid] = excl;
    }
    int total = buf[1023];
    __syncthreads();
    running += total;
  }
}

// ---------------- scatter edges into CSR (store src per dst-bucket) ----------------
__global__ void scatter_kernel(const int* __restrict__ src, const int* __restrict__ dst,
                               int* __restrict__ cur, int* __restrict__ csr, int e) {
  int i = blockIdx.x * blockDim.x + threadIdx.x;
  if (i < e) {
    int d = dst[i];
    int pos = atomicAdd(&cur[d], 1);
    csr[pos] = src[i];
  }
}

// ---------------- GEMM: H(N x M fp32) = Xbf(N x 128 bf16) @ W via Wt(M x 128 bf16) ----------------
template<int M>
__global__ __launch_bounds__(256) void gemm_kernel(const short* __restrict__ X,
                                                   const short* __restrict__ Wt,
                                                   float* __restrict__ H, int nrows) {
  int wave = blockIdx.x * 4 + (threadIdx.x >> 6);
  int lane = threadIdx.x & 63;
  if (wave * 16 >= nrows) return;
  int m16 = lane & 15, quad = lane >> 4;

  bf16x8 a[4];
  size_t arow = (size_t)(wave * 16 + m16) * K_DIM + quad * 8;
#pragma unroll
  for (int kc = 0; kc < 4; kc++) a[kc] = *(const bf16x8*)(X + arow + kc * 32);

#pragma unroll
  for (int nt = 0; nt < M / 16; nt++) {
    f32x4 acc = {0.f, 0.f, 0.f, 0.f};
    size_t brow = (size_t)(nt * 16 + m16) * K_DIM + quad * 8;
#pragma unroll
    for (int kc = 0; kc < 4; kc++) {
      bf16x8 b = *(const bf16x8*)(Wt + brow + kc * 32);
      acc = __builtin_amdgcn_mfma_f32_16x16x32_bf16(a[kc], b, acc, 0, 0, 0);
    }
    int col = nt * 16 + m16;
#pragma unroll
    for (int r = 0; r < 4; r++) {
      int row = wave * 16 + quad * 4 + r;
      H[(size_t)row * M + col] = acc[r];
    }
  }
}

// ---------------- per-node attention scores: s_i = <h, a[:M]>, s_j = <h, a[M:]> ----------------
template<int M>
__global__ __launch_bounds__(256) void score_kernel(const float* __restrict__ H,
                                                    const float* __restrict__ att,
                                                    float* __restrict__ s_i, float* __restrict__ s_j, int n) {
  using T = typename VT<M>::T;
  constexpr int V = VT<M>::V;
  int wave = blockIdx.x * 4 + (threadIdx.x >> 6);
  int lane = threadIdx.x & 63;
  if (wave >= n) return;
  int c = lane * V;
  T h  = *(const T*)(H + (size_t)wave * M + c);
  T aA = *(const T*)(att + c);
  T aB = *(const T*)(att + M + c);
  float si = 0.f, sj = 0.f;
#pragma unroll
  for (int k = 0; k < V; k++) { si += h[k] * aA[k]; sj += h[k] * aB[k]; }
#pragma unroll
  for (int o = 32; o > 0; o >>= 1) {
    si += __shfl_xor(si, o);
    sj += __shfl_xor(sj, o);
  }
  if (lane == 0) { s_i[wave] = si; s_j[wave] = sj; }
}

// ---------------- per-node aggregation + mu + ixz/skl accumulation ----------------
template<int M>  // M = 2C
__global__ __launch_bounds__(256) void aggr_kernel(const float* __restrict__ H,
                                                   const int* __restrict__ csr,
                                                   const int* __restrict__ off,
                                                   const int* __restrict__ deg,
                                                   const float* __restrict__ s_i,
                                                   const float* __restrict__ s_j,
                                                   const float* __restrict__ bias,
                                                   float* __restrict__ mu,
                                                   float* __restrict__ accum,  // [0]=ixz_sum [1]=skl_sum
                                                   int n) {
  using T = typename VT<M>::T;
  constexpr int V = VT<M>::V;
  constexpr int C = M / 2;
  int wave = blockIdx.x * 4 + (threadIdx.x >> 6);
  int lane = threadIdx.x & 63;
  if (wave >= n) return;

  int d = deg[wave];
  float norm = 1.0f / (float)d;
  float si = s_i[wave];
  int start = off[wave];

  T acc;
#pragma unroll
  for (int k = 0; k < V; k++) acc[k] = 0.f;
  float skl = 0.f;
  const float q = 1.0f / (1.0f + __expf(-(1.0f / 15.0f)));  // sigmoid(1/NBSZ)

  for (int e = 0; e < d; e++) {
    int src = csr[start + e];
    float sj = s_j[src];
    float lg = si + sj;
    lg = lg > 0.f ? lg : 0.2f * lg;          // leaky_relu
    float p = 1.0f / (1.0f + __expf(-lg));   // sigmoid
    p = fminf(fmaxf(p, 0.01f), 0.99f);       // clip
    float w = p * norm;                      // alpha
    T hv = *(const T*)(H + (size_t)src * M + lane * V);
#pragma unroll
    for (int k = 0; k < V; k++) acc[k] += w * hv[k];
    skl += p * __logf(p / q) + (1.0f - p) * __logf((1.0f - p) / (1.0f - q));
  }

  float ixz = 0.f;
  int c0 = lane * V;
  if (c0 < C) {
    T m;
#pragma unroll
    for (int k = 0; k < V; k++) {
      float a = acc[k] + bias[c0 + k];
      m[k] = a;
      ixz += 0.5f * a * a - 0.5f;
    }
    *(T*)(mu + (size_t)wave * C + c0) = m;
  } else {
#pragma unroll
    for (int k = 0; k < V; k++) {
      float a = acc[k] + bias[c0 + k];
      float sp = (a > 20.f) ? a : log1pf(__expf(a));  // softplus
      sp += 1e-10f;
      ixz += -__logf(sp) + 0.5f * sp * sp;
    }
  }
#pragma unroll
  for (int o = 32; o > 0; o >>= 1) ixz += __shfl_xor(ixz, o);
  if (lane == 0) {
    atomicAdd(&accum[0], ixz);
    atomicAdd(&accum[1], skl);  // skl identical across lanes (computed redundantly)
  }
}

// ---------------- layer-1 temporal fusion + ReLU -> bf16 layer-2 inputs ----------------
__global__ void fuse1_kernel(const float* __restrict__ mu0, const float* __restrict__ mu1,
                             __hip_bfloat16* __restrict__ x0, __hip_bfloat16* __restrict__ x1, int n) {
  int i = blockIdx.x * blockDim.x + threadIdx.x;
  if (i < n) {
    float m0 = mu0[i], m1 = mu1[i];
    x0[i] = __float2bfloat16(fmaxf(m0, 0.f));
    x1[i] = __float2bfloat16(fmaxf(0.4f * m0 + 0.2f * m1, 0.f));
  }
}

// ---------------- layer-2 temporal fusion -> final output (fp32) ----------------
__global__ void fuse2_kernel(const float* __restrict__ mu0, const float* __restrict__ mu1,
                             float* __restrict__ out, int n) {
  int i = blockIdx.x * blockDim.x + threadIdx.x;
  if (i < n) {
    float m0 = mu0[i], m1 = mu1[i];
    out[i] = m0;
    out[n + i] = 0.4f * m0 + 0.2f * m1;
  }
}

// ---------------- scalars ----------------
__global__ void finalize_kernel(const float* __restrict__ accum, float* __restrict__ out2) {
  out2[0] = (accum[0] + accum[2] + accum[4] + accum[6]) / (4.0f * (float)N_NODES);
  out2[1] = (accum[1] + accum[3] + accum[5] + accum[7]) / (4.0f * (float)N_EDGES);
}

extern "C" void kernel_launch(void* const* d_in, const int* in_sizes, int n_in,
                              void* d_out, int out_size, void* d_ws, size_t ws_size,
                              hipStream_t stream) {
  const float* x_all = (const float*)d_in[0];
  const int* ei      = (const int*)d_in[1];
  const float* W1    = (const float*)d_in[2];
  const float* att1  = (const float*)d_in[3];
  const float* b1    = (const float*)d_in[4];
  const float* W2    = (const float*)d_in[5];
  const float* att2  = (const float*)d_in[6];
  const float* b2    = (const float*)d_in[7];
  float* out         = (float*)d_out;

  char* ws = (char*)d_ws;
  size_t off = 0;
  auto alloc = [&](size_t bytes) {
    char* p = ws + off;
    off = (off + bytes + 255) & ~(size_t)255;
    return p;
  };
  __hip_bfloat16* wt1 = (__hip_bfloat16*)alloc(256 * 128 * sizeof(short));
  __hip_bfloat16* wt2 = (__hip_bfloat16*)alloc(128 * 128 * sizeof(short));
  __hip_bfloat16* xbf = (__hip_bfloat16*)alloc((size_t)N_NODES * 128 * sizeof(short));
  float* h      = (float*)alloc((size_t)N_NODES * 256 * sizeof(float));
  float* si     = (float*)alloc(N_NODES * sizeof(float));
  float* sj     = (float*)alloc(N_NODES * sizeof(float));
  float* mu1_0  = (float*)alloc((size_t)N_NODES * 128 * sizeof(float));
  float* mu1_1  = (float*)alloc((size_t)N_NODES * 128 * sizeof(float));
  __hip_bfloat16* x2_0 = (__hip_bfloat16*)alloc((size_t)N_NODES * 128 * sizeof(short));
  __hip_bfloat16* x2_1 = (__hip_bfloat16*)alloc((size_t)N_NODES * 128 * sizeof(short));
  float* mu2_0  = (float*)alloc((size_t)N_NODES * 64 * sizeof(float));
  float* mu2_1  = (float*)alloc((size_t)N_NODES * 64 * sizeof(float));
  int* degp[2]  = {(int*)alloc(N_NODES * 4), (int*)alloc(N_NODES * 4)};
  int* offp[2]  = {(int*)alloc(N_NODES * 4), (int*)alloc(N_NODES * 4)};
  int* curp[2]  = {(int*)alloc(N_NODES * 4), (int*)alloc(N_NODES * 4)};
  int* csrp[2]  = {(int*)alloc(N_EDGES * 4), (int*)alloc(N_EDGES * 4)};
  float* accum  = (float*)alloc(8 * sizeof(float));

  hipMemsetAsync(degp[0], 0, N_NODES * 4, stream);
  hipMemsetAsync(degp[1], 0, N_NODES * 4, stream);
  hipMemsetAsync(accum, 0, 8 * sizeof(float), stream);

  transpose_w_kernel<<<(128 * 256 + 255) / 256, 256, 0, stream>>>(W1, wt1, 128, 256);
  transpose_w_kernel<<<(128 * 128 + 255) / 256, 256, 0, stream>>>(W2, wt2, 128, 128);

  for (int t = 0; t < 2; t++) {
    const int* src = ei + (size_t)t * 2 * N_EDGES;
    const int* dst = src + N_EDGES;
    deg_kernel<<<(N_EDGES + 255) / 256, 256, 0, stream>>>(dst, degp[t], N_EDGES);
    scan_kernel<<<1, 1024, 0, stream>>>(degp[t], offp[t], curp[t], N_NODES);
    scatter_kernel<<<(N_EDGES + 255) / 256, 256, 0, stream>>>(src, dst, curp[t], csrp[t], N_EDGES);
  }

  // ---- layer 1 (C = 128, M = 256) ----
  float* mu1[2] = {mu1_0, mu1_1};
  for (int t = 0; t < 2; t++) {
    const float* xt = x_all + (size_t)t * N_NODES * K_DIM;
    convert_kernel<<<(N_NODES * 128 + 255) / 256, 256, 0, stream>>>(xt, xbf, N_NODES * 128);
    gemm_kernel<256><<<469, 256, 0, stream>>>((const short*)xbf, (const short*)wt1, h, N_NODES);
    score_kernel<256><<<7500, 256, 0, stream>>>(h, att1, si, sj, N_NODES);
    aggr_kernel<256><<<7500, 256, 0, stream>>>(h, csrp[t], offp[t], degp[t], si, sj, b1,
                                               mu1[t], accum + 2 * t, N_NODES);
  }
  fuse1_kernel<<<(N_NODES * 128 + 255) / 256, 256, 0, stream>>>(mu1_0, mu1_1, x2_0, x2_1, N_NODES * 128);

  // ---- layer 2 (C = 64, M = 128) ----
  float* mu2[2] = {mu2_0, mu2_1};
  __hip_bfloat16* x2[2] = {x2_0, x2_1};
  for (int t = 0; t < 2; t++) {
    gemm_kernel<128><<<469, 256, 0, stream>>>((const short*)x2[t], (const short*)wt2, h, N_NODES);
    score_kernel<128><<<7500, 256, 0, stream>>>(h, att2, si, sj, N_NODES);
    aggr_kernel<128><<<7500, 256, 0, stream>>>(h, csrp[t], offp[t], degp[t], si, sj, b2,
                                               mu2[t], accum + 4 + 2 * t, N_NODES);
  }
  fuse2_kernel<<<(N_NODES * 64 + 255) / 256, 256, 0, stream>>>(mu2_0, mu2_1, out, N_NODES * 64);
  finalize_kernel<<<1, 1, 0, stream>>>(accum, out + (size_t)2 * N_NODES * 64);
}

// Round 3
// 1025.229 us; speedup vs baseline: 3.4500x; 3.4500x over previous
//
#include <hip/hip_runtime.h>
#include <hip/hip_bf16.h>

#define N_NODES 30000
#define N_EDGES 510000
#define K_DIM   128

typedef short bf16x8 __attribute__((ext_vector_type(8)));
typedef float f32x4  __attribute__((ext_vector_type(4)));
typedef float f32x2  __attribute__((ext_vector_type(2)));

template<int M> struct VT;
template<> struct VT<256> { using T = f32x4; static constexpr int V = 4; };
template<> struct VT<128> { using T = f32x2; static constexpr int V = 2; };

// ---------------- fp32 -> bf16 convert ----------------
__global__ void convert_kernel(const float* __restrict__ x, __hip_bfloat16* __restrict__ y, int n) {
  int i = blockIdx.x * blockDim.x + threadIdx.x;
  if (i < n) y[i] = __float2bfloat16(x[i]);
}

// ---------------- W transpose (K x M fp32) -> (M x K bf16) ----------------
__global__ void transpose_w_kernel(const float* __restrict__ W,
                                   __hip_bfloat16* __restrict__ Wt, int K, int M) {
  int i = blockIdx.x * blockDim.x + threadIdx.x;
  if (i < K * M) {
    int k = i / M, m = i - k * M;
    Wt[m * K + k] = __float2bfloat16(W[i]);
  }
}

// ---------------- degree (in-degree by dst) ----------------
__global__ void deg_kernel(const int* __restrict__ dst, int* __restrict__ deg, int e) {
  int i = blockIdx.x * blockDim.x + threadIdx.x;
  if (i < e) atomicAdd(&deg[dst[i]], 1);
}

// ---------------- exclusive scan over deg -> offsets (+cursor copy), 1 block ----------------
__global__ void scan_kernel(const int* __restrict__ deg, int* __restrict__ off,
                            int* __restrict__ cur, int n) {
  __shared__ int buf[1024];
  int tid = threadIdx.x;
  int running = 0;
  for (int base = 0; base < n; base += 1024) {
    int v = (base + tid < n) ? deg[base + tid] : 0;
    buf[tid] = v;
    __syncthreads();
    for (int o = 1; o < 1024; o <<= 1) {
      int t = (tid >= o) ? buf[tid - o] : 0;
      __syncthreads();
      buf[tid] += t;
      __syncthreads();
    }
    int incl = buf[tid];
    if (base + tid < n) {
      int excl = running + incl - v;
      off[base + tid] = excl;
      cur[base + tid] = excl;
    }
    int total = buf[1023];
    __syncthreads();
    running += total;
  }
}

// ---------------- scatter edges into CSR; record edge -> CSR position ----------------
__global__ void scatter_kernel(const int* __restrict__ src, const int* __restrict__ dst,
                               int* __restrict__ cur, int* __restrict__ csr,
                               int* __restrict__ pos, int e) {
  int i = blockIdx.x * blockDim.x + threadIdx.x;
  if (i < e) {
    int d = dst[i];
    int p = atomicAdd(&cur[d], 1);
    csr[p] = src[i];
    pos[i] = p;
  }
}

// ---------------- GEMM: H(N x M fp32) = Xbf(N x 128 bf16) @ W via Wt(M x 128 bf16) ----------------
template<int M>
__global__ __launch_bounds__(256) void gemm_kernel(const short* __restrict__ X,
                                                   const short* __restrict__ Wt,
                                                   float* __restrict__ H, int nrows) {
  int wave = blockIdx.x * 4 + (threadIdx.x >> 6);
  int lane = threadIdx.x & 63;
  if (wave * 16 >= nrows) return;
  int m16 = lane & 15, quad = lane >> 4;

  bf16x8 a[4];
  size_t arow = (size_t)(wave * 16 + m16) * K_DIM + quad * 8;
#pragma unroll
  for (int kc = 0; kc < 4; kc++) a[kc] = *(const bf16x8*)(X + arow + kc * 32);

#pragma unroll
  for (int nt = 0; nt < M / 16; nt++) {
    f32x4 acc = {0.f, 0.f, 0.f, 0.f};
    size_t brow = (size_t)(nt * 16 + m16) * K_DIM + quad * 8;
#pragma unroll
    for (int kc = 0; kc < 4; kc++) {
      bf16x8 b = *(const bf16x8*)(Wt + brow + kc * 32);
      acc = __builtin_amdgcn_mfma_f32_16x16x32_bf16(a[kc], b, acc, 0, 0, 0);
    }
    int col = nt * 16 + m16;
#pragma unroll
    for (int r = 0; r < 4; r++) {
      int row = wave * 16 + quad * 4 + r;
      H[(size_t)row * M + col] = acc[r];
    }
  }
}

// ---------------- per-node attention scores ----------------
template<int M>
__global__ __launch_bounds__(256) void score_kernel(const float* __restrict__ H,
                                                    const float* __restrict__ att,
                                                    float* __restrict__ s_i, float* __restrict__ s_j, int n) {
  using T = typename VT<M>::T;
  constexpr int V = VT<M>::V;
  int wave = blockIdx.x * 4 + (threadIdx.x >> 6);
  int lane = threadIdx.x & 63;
  if (wave >= n) return;
  int c = lane * V;
  T h  = *(const T*)(H + (size_t)wave * M + c);
  T aA = *(const T*)(att + c);
  T aB = *(const T*)(att + M + c);
  float si = 0.f, sj = 0.f;
#pragma unroll
  for (int k = 0; k < V; k++) { si += h[k] * aA[k]; sj += h[k] * aB[k]; }
#pragma unroll
  for (int o = 32; o > 0; o >>= 1) {
    si += __shfl_xor(si, o);
    sj += __shfl_xor(sj, o);
  }
  if (lane == 0) { s_i[wave] = si; s_j[wave] = sj; }
}

// ---------------- per-edge attention prob p + skl accumulation (edge-parallel) ----------------
__global__ __launch_bounds__(256) void edge_p_kernel(const int* __restrict__ src,
                                                     const int* __restrict__ dst,
                                                     const int* __restrict__ pos,
                                                     const float* __restrict__ s_i,
                                                     const float* __restrict__ s_j,
                                                     float* __restrict__ w_csr,
                                                     float* __restrict__ skl_accum, int e) {
  __shared__ float red[4];
  int i = blockIdx.x * blockDim.x + threadIdx.x;
  float skl = 0.f;
  const float q = 1.0f / (1.0f + __expf(-(1.0f / 15.0f)));
  if (i < e) {
    float lg = s_i[dst[i]] + s_j[src[i]];
    lg = lg > 0.f ? lg : 0.2f * lg;          // leaky_relu
    float p = 1.0f / (1.0f + __expf(-lg));   // sigmoid
    p = fminf(fmaxf(p, 0.01f), 0.99f);       // clip
    w_csr[pos[i]] = p;
    skl = p * __logf(p / q) + (1.0f - p) * __logf((1.0f - p) / (1.0f - q));
  }
#pragma unroll
  for (int o = 32; o > 0; o >>= 1) skl += __shfl_xor(skl, o);
  int wid = threadIdx.x >> 6, lane = threadIdx.x & 63;
  if (lane == 0) red[wid] = skl;
  __syncthreads();
  if (threadIdx.x == 0)
    atomicAdd(skl_accum, red[0] + red[1] + red[2] + red[3]);
}

// ---------------- per-node weighted gather + mu + ixz ----------------
template<int M>  // M = 2C
__global__ __launch_bounds__(256) void aggr_kernel(const float* __restrict__ H,
                                                   const int* __restrict__ csr,
                                                   const int* __restrict__ off,
                                                   const int* __restrict__ deg,
                                                   const float* __restrict__ w,
                                                   const float* __restrict__ bias,
                                                   float* __restrict__ mu,
                                                   float* __restrict__ ixz_accum,
                                                   int n) {
  using T = typename VT<M>::T;
  constexpr int V = VT<M>::V;
  constexpr int C = M / 2;
  constexpr int U = 8;  // chunk: 8 independent row-gathers in flight
  __shared__ float red[4];
  int wid = threadIdx.x >> 6;
  int wave = blockIdx.x * 4 + wid;
  int lane = threadIdx.x & 63;
  float ixz = 0.f;

  if (wave < n) {
    int d = deg[wave];
    float norm = 1.0f / (float)d;
    int start = off[wave];
    int c0 = lane * V;

    T acc;
#pragma unroll
    for (int k = 0; k < V; k++) acc[k] = 0.f;

    for (int e0 = 0; e0 < d; e0 += U) {
      int idxs[U];
      float ws[U];
#pragma unroll
      for (int u = 0; u < U; u++) {
        int ee = e0 + u;
        bool v = ee < d;
        idxs[u] = v ? csr[start + ee] : 0;
        ws[u]   = v ? w[start + ee] : 0.f;
      }
      T hv[U];
#pragma unroll
      for (int u = 0; u < U; u++)
        hv[u] = *(const T*)(H + (size_t)idxs[u] * M + c0);
#pragma unroll
      for (int u = 0; u < U; u++) {
#pragma unroll
        for (int k = 0; k < V; k++) acc[k] += ws[u] * hv[u][k];
      }
    }

    if (c0 < C) {
      T m;
#pragma unroll
      for (int k = 0; k < V; k++) {
        float a = acc[k] * norm + bias[c0 + k];
        m[k] = a;
        ixz += 0.5f * a * a - 0.5f;
      }
      *(T*)(mu + (size_t)wave * C + c0) = m;
    } else {
#pragma unroll
      for (int k = 0; k < V; k++) {
        float a = acc[k] * norm + bias[c0 + k];
        float sp = (a > 20.f) ? a : log1pf(__expf(a));  // softplus
        sp += 1e-10f;
        ixz += -__logf(sp) + 0.5f * sp * sp;
      }
    }
  }
#pragma unroll
  for (int o = 32; o > 0; o >>= 1) ixz += __shfl_xor(ixz, o);
  if (lane == 0) red[wid] = ixz;
  __syncthreads();
  if (threadIdx.x == 0)
    atomicAdd(ixz_accum, red[0] + red[1] + red[2] + red[3]);
}

// ---------------- layer-1 temporal fusion + ReLU -> bf16 layer-2 inputs ----------------
__global__ void fuse1_kernel(const float* __restrict__ mu0, const float* __restrict__ mu1,
                             __hip_bfloat16* __restrict__ x0, __hip_bfloat16* __restrict__ x1, int n) {
  int i = blockIdx.x * blockDim.x + threadIdx.x;
  if (i < n) {
    float m0 = mu0[i], m1 = mu1[i];
    x0[i] = __float2bfloat16(fmaxf(m0, 0.f));
    x1[i] = __float2bfloat16(fmaxf(0.4f * m0 + 0.2f * m1, 0.f));
  }
}

// ---------------- layer-2 temporal fusion -> final output (fp32) ----------------
__global__ void fuse2_kernel(const float* __restrict__ mu0, const float* __restrict__ mu1,
                             float* __restrict__ out, int n) {
  int i = blockIdx.x * blockDim.x + threadIdx.x;
  if (i < n) {
    float m0 = mu0[i], m1 = mu1[i];
    out[i] = m0;
    out[n + i] = 0.4f * m0 + 0.2f * m1;
  }
}

// ---------------- scalars ----------------
__global__ void finalize_kernel(const float* __restrict__ accum, float* __restrict__ out2) {
  out2[0] = (accum[0] + accum[2] + accum[4] + accum[6]) / (4.0f * (float)N_NODES);
  out2[1] = (accum[1] + accum[3] + accum[5] + accum[7]) / (4.0f * (float)N_EDGES);
}

extern "C" void kernel_launch(void* const* d_in, const int* in_sizes, int n_in,
                              void* d_out, int out_size, void* d_ws, size_t ws_size,
                              hipStream_t stream) {
  const float* x_all = (const float*)d_in[0];
  const int* ei      = (const int*)d_in[1];
  const float* W1    = (const float*)d_in[2];
  const float* att1  = (const float*)d_in[3];
  const float* b1    = (const float*)d_in[4];
  const float* W2    = (const float*)d_in[5];
  const float* att2  = (const float*)d_in[6];
  const float* b2    = (const float*)d_in[7];
  float* out         = (float*)d_out;

  char* ws = (char*)d_ws;
  size_t off = 0;
  auto alloc = [&](size_t bytes) {
    char* p = ws + off;
    off = (off + bytes + 255) & ~(size_t)255;
    return p;
  };
  __hip_bfloat16* wt1 = (__hip_bfloat16*)alloc(256 * 128 * sizeof(short));
  __hip_bfloat16* wt2 = (__hip_bfloat16*)alloc(128 * 128 * sizeof(short));
  __hip_bfloat16* xbf = (__hip_bfloat16*)alloc((size_t)N_NODES * 128 * sizeof(short));
  float* h      = (float*)alloc((size_t)N_NODES * 256 * sizeof(float));
  float* si     = (float*)alloc(N_NODES * sizeof(float));
  float* sj     = (float*)alloc(N_NODES * sizeof(float));
  float* mu1_0  = (float*)alloc((size_t)N_NODES * 128 * sizeof(float));
  float* mu1_1  = (float*)alloc((size_t)N_NODES * 128 * sizeof(float));
  __hip_bfloat16* x2_0 = (__hip_bfloat16*)alloc((size_t)N_NODES * 128 * sizeof(short));
  __hip_bfloat16* x2_1 = (__hip_bfloat16*)alloc((size_t)N_NODES * 128 * sizeof(short));
  float* mu2_0  = (float*)alloc((size_t)N_NODES * 64 * sizeof(float));
  float* mu2_1  = (float*)alloc((size_t)N_NODES * 64 * sizeof(float));
  int* degp[2]  = {(int*)alloc(N_NODES * 4), (int*)alloc(N_NODES * 4)};
  int* offp[2]  = {(int*)alloc(N_NODES * 4), (int*)alloc(N_NODES * 4)};
  int* curp[2]  = {(int*)alloc(N_NODES * 4), (int*)alloc(N_NODES * 4)};
  int* csrp[2]  = {(int*)alloc(N_EDGES * 4), (int*)alloc(N_EDGES * 4)};
  int* posp[2]  = {(int*)alloc(N_EDGES * 4), (int*)alloc(N_EDGES * 4)};
  float* w_csr  = (float*)alloc(N_EDGES * 4);
  float* accum  = (float*)alloc(8 * sizeof(float));

  hipMemsetAsync(degp[0], 0, N_NODES * 4, stream);
  hipMemsetAsync(degp[1], 0, N_NODES * 4, stream);
  hipMemsetAsync(accum, 0, 8 * sizeof(float), stream);

  transpose_w_kernel<<<(128 * 256 + 255) / 256, 256, 0, stream>>>(W1, wt1, 128, 256);
  transpose_w_kernel<<<(128 * 128 + 255) / 256, 256, 0, stream>>>(W2, wt2, 128, 128);

  const int* srcp[2], *dstp[2];
  for (int t = 0; t < 2; t++) {
    srcp[t] = ei + (size_t)t * 2 * N_EDGES;
    dstp[t] = srcp[t] + N_EDGES;
    deg_kernel<<<(N_EDGES + 255) / 256, 256, 0, stream>>>(dstp[t], degp[t], N_EDGES);
    scan_kernel<<<1, 1024, 0, stream>>>(degp[t], offp[t], curp[t], N_NODES);
    scatter_kernel<<<(N_EDGES + 255) / 256, 256, 0, stream>>>(srcp[t], dstp[t], curp[t],
                                                              csrp[t], posp[t], N_EDGES);
  }

  // ---- layer 1 (C = 128, M = 256) ----
  float* mu1[2] = {mu1_0, mu1_1};
  for (int t = 0; t < 2; t++) {
    const float* xt = x_all + (size_t)t * N_NODES * K_DIM;
    convert_kernel<<<(N_NODES * 128 + 255) / 256, 256, 0, stream>>>(xt, xbf, N_NODES * 128);
    gemm_kernel<256><<<469, 256, 0, stream>>>((const short*)xbf, (const short*)wt1, h, N_NODES);
    score_kernel<256><<<7500, 256, 0, stream>>>(h, att1, si, sj, N_NODES);
    edge_p_kernel<<<(N_EDGES + 255) / 256, 256, 0, stream>>>(srcp[t], dstp[t], posp[t], si, sj,
                                                             w_csr, accum + 2 * t + 1, N_EDGES);
    aggr_kernel<256><<<7500, 256, 0, stream>>>(h, csrp[t], offp[t], degp[t], w_csr, b1,
                                               mu1[t], accum + 2 * t, N_NODES);
  }
  fuse1_kernel<<<(N_NODES * 128 + 255) / 256, 256, 0, stream>>>(mu1_0, mu1_1, x2_0, x2_1, N_NODES * 128);

  // ---- layer 2 (C = 64, M = 128) ----
  float* mu2[2] = {mu2_0, mu2_1};
  __hip_bfloat16* x2[2] = {x2_0, x2_1};
  for (int t = 0; t < 2; t++) {
    gemm_kernel<128><<<469, 256, 0, stream>>>((const short*)x2[t], (const short*)wt2, h, N_NODES);
    score_kernel<128><<<7500, 256, 0, stream>>>(h, att2, si, sj, N_NODES);
    edge_p_kernel<<<(N_EDGES + 255) / 256, 256, 0, stream>>>(srcp[t], dstp[t], posp[t], si, sj,
                                                             w_csr, accum + 4 + 2 * t + 1, N_EDGES);
    aggr_kernel<128><<<7500, 256, 0, stream>>>(h, csrp[t], offp[t], degp[t], w_csr, b2,
                                               mu2[t], accum + 4 + 2 * t, N_NODES);
  }
  fuse2_kernel<<<(N_NODES * 64 + 255) / 256, 256, 0, stream>>>(mu2_0, mu2_1, out, N_NODES * 64);
  finalize_kernel<<<1, 1, 0, stream>>>(accum, out + (size_t)2 * N_NODES * 64);
}